// Round 16
// baseline (192.037 us; speedup 1.0000x reference)
//
#include <hip/hip_runtime.h>
#include <math.h>

#define NH 16
#define HD 64
#define NB 2
#define LSEQ 2048
#define DM 1024
#define NLM 32

// out layout: y [4194304] | M_new [131072] | Z_new [2048]
#define OUT_M 4194304
#define OUT_Z 4325376

typedef unsigned short u16;
typedef short bf16x8 __attribute__((ext_vector_type(8)));
typedef float f32x16 __attribute__((ext_vector_type(16)));
typedef unsigned short u16x4 __attribute__((ext_vector_type(4)));
typedef unsigned long long ull;

__device__ __forceinline__ float sigmoidf_(float x) { return 1.0f / (1.0f + __expf(-x)); }
__device__ __forceinline__ float phif_(float x) { return x > 0.0f ? x + 1.0f : __expf(x); }

__device__ __forceinline__ u16 f2b(float f) {
    union { float f; unsigned u; } v; v.f = f;
    unsigned r = v.u + 0x7FFFu + ((v.u >> 16) & 1u);
    return (u16)(r >> 16);
}
__device__ __forceinline__ float b2f(u16 b) {
    union { unsigned u; float f; } v; v.u = ((unsigned)b) << 16; return v.f;
}
__device__ __forceinline__ ull pack4(float a, float b, float c, float d) {
    return (ull)f2b(a) | ((ull)f2b(b) << 16) | ((ull)f2b(c) << 32) | ((ull)f2b(d) << 48);
}
__device__ __forceinline__ int cvtpkbf(float lo, float hi2) {
    int r;
    asm("v_cvt_pk_bf16_f32 %0, %1, %2" : "=v"(r) : "v"(lo), "v"(hi2));
    return r;
}
__device__ __forceinline__ void gload16(const u16* g, u16* l) {
    __builtin_amdgcn_global_load_lds(
        (const __attribute__((address_space(1))) void*)g,
        (__attribute__((address_space(3))) void*)l, 16, 0, 0);
}
// DMA-aware barrier: own vmcnt(0) (global_load_lds completion) + s_barrier.
__device__ __forceinline__ void sync_vm0() {
    __builtin_amdgcn_sched_barrier(0);
    asm volatile("s_waitcnt vmcnt(0)" ::: "memory");
    __builtin_amdgcn_s_barrier();
    __builtin_amdgcn_sched_barrier(0);
}
__device__ __forceinline__ void sync_lgkm0() {
    __builtin_amdgcn_sched_barrier(0);
    asm volatile("s_waitcnt lgkmcnt(0)" ::: "memory");
    __builtin_amdgcn_s_barrier();
    __builtin_amdgcn_sched_barrier(0);
}

// ---------------------------------------------------------------------------
// f32 -> bf16 convert: x | wq | wk | wv | wo into contiguous dst (8M elems)
// ---------------------------------------------------------------------------
__global__ __launch_bounds__(256) void cvt_all(
    const float* __restrict__ x, const float* __restrict__ wq,
    const float* __restrict__ wk, const float* __restrict__ wv,
    const float* __restrict__ wo, u16* __restrict__ dst) {
    size_t i = ((size_t)blockIdx.x * 256 + threadIdx.x) * 8;
    const float* src;
    size_t off;
    if (i < 4194304)      { src = x;  off = i; }
    else if (i < 5242880) { src = wq; off = i - 4194304; }
    else if (i < 6291456) { src = wk; off = i - 5242880; }
    else if (i < 7340032) { src = wv; off = i - 6291456; }
    else                  { src = wo; off = i - 7340032; }
    float4 a = *(const float4*)(src + off);
    float4 b = *(const float4*)(src + off + 4);
    u16 o[8] = {f2b(a.x), f2b(a.y), f2b(a.z), f2b(a.w),
                f2b(b.x), f2b(b.y), f2b(b.z), f2b(b.w)};
    *(int4*)(dst + i) = *(int4*)o;
}

// ---------------------------------------------------------------------------
// MFMA GEMM (T2 staging). Tile 128x128, BK=64, 4 waves 2x2.
// MODE 4: fused QKV. Writes q_base (normal, for combine), k_base (normal,
// landmarks), and PRE-SWIZZLED tile images for flash DMA staging:
//   qt: [bh][qtile16][128x64]  byte = row*128 + ((d>>3 ^ row&7)*16) + (d&7)*2
//   kt: [bh][t32]  [64x64]     byte = r*128  + ((d>>3 ^ r&7)*16)   + (d&7)*2
//   vt: [bh][t32]  V^T image   byte = (r>>5)*4096 + (d>>5)*2048 + (d&31)*64
//                                     + (((r&31)>>3 ^ (d>>3)&3)*16) + (r&7)*2
// q_rope scale folds 0.125*log2(e) (flash uses exp2). MODE 1: f32 out.
// ---------------------------------------------------------------------------
template <int MODE>
__global__ __launch_bounds__(256) void gemm_mfma(
    const u16* __restrict__ A, const u16* __restrict__ W,
    float* __restrict__ Cf, u16* __restrict__ qb, u16* __restrict__ qt_,
    u16* __restrict__ kbp, u16* __restrict__ kt, u16* __restrict__ vt,
    const float* __restrict__ fcos, const float* __restrict__ fsin) {
    __shared__ u16 As[128 * 64];   // 16 KB, linear (row*128B + chunk*16B)
    __shared__ u16 Ws[128 * 64];   // 16 KB
    const int tid = threadIdx.x;
    const int m0 = blockIdx.x * 128;
    const int n0 = blockIdx.y * 128;
    const int w = tid >> 6;
    const int lane = tid & 63;
    const int l31 = lane & 31;
    const int khalf = lane >> 5;
    const int wr0 = (w >> 1) * 64;
    const int wc0 = (w & 1) * 64;

    const u16* Ag = A + (size_t)m0 * DM;
    const u16* Wg = W + (size_t)n0 * DM;

    const int st_uoff[4] = {w * 4096, w * 4096 + 1024, w * 4096 + 2048, w * 4096 + 3072};
    int st_row[4], st_cc[4];
#pragma unroll
    for (int i = 0; i < 4; ++i) {
        const int off = st_uoff[i] + lane * 16;
        st_row[i] = off >> 7;
        st_cc[i] = ((off >> 4) & 7) ^ (st_row[i] & 7);
    }

    f32x16 acc[2][2];
#pragma unroll
    for (int mf = 0; mf < 2; ++mf)
#pragma unroll
        for (int nf = 0; nf < 2; ++nf)
#pragma unroll
            for (int i = 0; i < 16; ++i) acc[mf][nf][i] = 0.f;

    for (int k0 = 0; k0 < DM; k0 += 64) {
        __syncthreads();
#pragma unroll
        for (int i = 0; i < 4; ++i)
            gload16(Ag + (size_t)st_row[i] * DM + k0 + st_cc[i] * 8,
                    (u16*)((char*)As + st_uoff[i]));
#pragma unroll
        for (int i = 0; i < 4; ++i)
            gload16(Wg + (size_t)st_row[i] * DM + k0 + st_cc[i] * 8,
                    (u16*)((char*)Ws + st_uoff[i]));
        __syncthreads();
#pragma unroll
        for (int ko = 0; ko < 4; ++ko) {
            const int cl = ko * 2 + khalf;
            const int ra0 = wr0 + l31, ra1 = wr0 + 32 + l31;
            const int rb0 = wc0 + l31, rb1 = wc0 + 32 + l31;
            bf16x8 af0 = *(const bf16x8*)((char*)As + ra0 * 128 + ((cl ^ (ra0 & 7)) * 16));
            bf16x8 af1 = *(const bf16x8*)((char*)As + ra1 * 128 + ((cl ^ (ra1 & 7)) * 16));
            bf16x8 bf0 = *(const bf16x8*)((char*)Ws + rb0 * 128 + ((cl ^ (rb0 & 7)) * 16));
            bf16x8 bf1 = *(const bf16x8*)((char*)Ws + rb1 * 128 + ((cl ^ (rb1 & 7)) * 16));
            acc[0][0] = __builtin_amdgcn_mfma_f32_32x32x16_bf16(af0, bf0, acc[0][0], 0, 0, 0);
            acc[0][1] = __builtin_amdgcn_mfma_f32_32x32x16_bf16(af0, bf1, acc[0][1], 0, 0, 0);
            acc[1][0] = __builtin_amdgcn_mfma_f32_32x32x16_bf16(af1, bf0, acc[1][0], 0, 0, 0);
            acc[1][1] = __builtin_amdgcn_mfma_f32_32x32x16_bf16(af1, bf1, acc[1][1], 0, 0, 0);
        }
    }

#pragma unroll
    for (int mf = 0; mf < 2; ++mf) {
#pragma unroll
        for (int nf = 0; nf < 2; ++nf) {
            const int nn = n0 + wc0 + nf * 32 + l31;
#pragma unroll
            for (int reg = 0; reg < 16; ++reg) {
                const int m = m0 + wr0 + mf * 32 + (reg & 3) + 8 * (reg >> 2) + 4 * khalf;
                const float val = acc[mf][nf][reg];
                if (MODE == 1) {
                    Cf[(size_t)m * DM + nn] = val;
                } else {
                    const int b = m >> 11, l = m & (LSEQ - 1);
                    const int mat = nn >> 10;       // 0=q 1=k 2=v
                    const int n = nn & 1023;
                    const int h = n >> 6, d = n & 63;
                    const int bh = b * NH + h;
                    const size_t hs = (((size_t)bh) * LSEQ + l) * HD + d;
                    const float p = __shfl_xor(val, 1);   // full-exec; partner d^1
                    if (mat == 2) {
                        const int t = l >> 6, r = l & 63;
                        vt[((size_t)(bh * 32 + t)) * 4096 + (r >> 5) * 2048 +
                           (d >> 5) * 1024 + (d & 31) * 32 +
                           ((((r & 31) >> 3) ^ ((d >> 3) & 3)) * 8) + (r & 7)] = f2b(val);
                    } else {
                        const float c = fcos[l * 32 + (d >> 1)];
                        const float s = fsin[l * 32 + (d >> 1)];
                        float o = (d & 1) ? (p * s + val * c) : (val * c - p * s);
                        if (mat == 0) {
                            o *= 0.18033688f;   // 0.125 * log2(e)
                            qb[hs] = f2b(val);
                            const int qtile = l >> 7, row = l & 127;
                            qt_[((size_t)(bh * 16 + qtile)) * 8192 + row * 64 +
                                (((d >> 3) ^ (row & 7)) * 8) + (d & 7)] = f2b(o);
                        } else {
                            kbp[hs] = f2b(val);
                            const int t = l >> 6, r = l & 63;
                            kt[((size_t)(bh * 32 + t)) * 4096 + r * 64 +
                               (((d >> 3) ^ (r & 7)) * 8) + (d & 7)] = f2b(o);
                        }
                    }
                }
            }
        }
    }
}

// ---------------------------------------------------------------------------
// Landmarks: one block per (b,h); grid (b,h,m). K from k_base (normal);
// V from the vt tile image (16B chunks = 8 consecutive keys at fixed d).
// ---------------------------------------------------------------------------
__global__ __launch_bounds__(256) void landmarks(
    const u16* __restrict__ kbase, const u16* __restrict__ vt,
    float* __restrict__ lkq, float* __restrict__ lvq) {
    __shared__ float redk[4][HD];
    __shared__ float redv[8][HD];
    const int bh = blockIdx.x >> 5;
    const int m = blockIdx.x & 31;
    const int tid = threadIdx.x;
    const int ls = tid >> 6;
    const int d = tid & 63;
    const u16* kb = kbase + ((size_t)bh * LSEQ + m * 64) * HD;
    float sk = 0.f;
    for (int l = ls; l < 64; l += 4) sk += b2f(kb[(size_t)l * HD + d]);
    redk[ls][d] = sk;

    const u16* vtile = vt + ((size_t)(bh * 32 + m)) * 4096;
#pragma unroll
    for (int j = 0; j < 2; ++j) {
        const int slot = tid + 256 * j;          // 0..511 = kgroup(8) x d(64)
        const int kg = slot >> 6, dd = slot & 63;
        const u16* p = vtile + (kg >> 2) * 2048 + (dd >> 5) * 1024 + (dd & 31) * 32 +
                       (((kg & 3) ^ ((dd >> 3) & 3)) * 8);
        int4 raw = *(const int4*)p;
        const u16* u = (const u16*)&raw;
        float s = 0.f;
#pragma unroll
        for (int e = 0; e < 8; ++e) s += b2f(u[e]);
        redv[kg][dd] = s;
    }
    __syncthreads();
    if (tid < 64) {
        float mk = (redk[0][d] + redk[1][d] + redk[2][d] + redk[3][d]) * (1.0f / 64.0f);
        float sv = 0.f;
#pragma unroll
        for (int kg = 0; kg < 8; ++kg) sv += redv[kg][d];
        lkq[((size_t)bh * NLM + m) * HD + d] = phif_(mk);
        lvq[((size_t)bh * NLM + m) * HD + d] = sv * (1.0f / 64.0f);
    }
}

// ---------------------------------------------------------------------------
__global__ __launch_bounds__(256) void mem_update(
    const float* __restrict__ lkq, const float* __restrict__ lvq,
    const float* __restrict__ M_old, const float* __restrict__ Z_old,
    const float* __restrict__ decay_p, float* __restrict__ out) {
    __shared__ float lk[NLM][HD];
    __shared__ float lv[NLM][HD];
    const int bh = blockIdx.x;
    const int tid = threadIdx.x;
    const float decay = sigmoidf_(decay_p[0]);
#pragma unroll
    for (int i = 0; i < 8; ++i) {
        int idx = tid + 256 * i;
        lk[idx >> 6][idx & 63] = lkq[(size_t)bh * (NLM * HD) + idx];
        lv[idx >> 6][idx & 63] = lvq[(size_t)bh * (NLM * HD) + idx];
    }
    __syncthreads();
    const size_t mo = (size_t)bh * HD * HD;
#pragma unroll
    for (int p = 0; p < 16; ++p) {
        int idx = tid + 256 * p;
        int dd = idx >> 6, e = idx & 63;
        float s = 0.f;
#pragma unroll
        for (int m = 0; m < NLM; ++m) s = fmaf(lk[m][dd], lv[m][e], s);
        out[OUT_M + mo + idx] = M_old[mo + idx] * decay + s;
    }
    if (tid < 64) {
        float s = 0.f;
#pragma unroll
        for (int m = 0; m < NLM; ++m) s += lk[m][tid];
        out[OUT_Z + (size_t)bh * HD + tid] = Z_old[(size_t)bh * HD + tid] * decay + s;
    }
}

// ---------------------------------------------------------------------------
// Combine: merge split-KV partials (normalized bf16 O + (m,l) per half) and
// add gate * (phiQ @ M_old)/den. Writes ctxb (bf16).
// ---------------------------------------------------------------------------
__global__ __launch_bounds__(256) void combine(
    const u16* __restrict__ qbase, const u16* __restrict__ opart,
    const float2* __restrict__ ml, const float* __restrict__ M_old,
    const float* __restrict__ Z_old, const float* __restrict__ gate_p,
    u16* __restrict__ ctxb) {
    __shared__ float phiQ[64][68];
    __shared__ float Ms[64][64];
    __shared__ float Zs[64];
    const int l0 = blockIdx.x * 64;
    const int bh = blockIdx.y;
    const int b = bh >> 4, h = bh & 15;
    const int tid = threadIdx.x;
    const float gate = sigmoidf_(gate_p[0]);

    {
        const int r = tid >> 2, c0 = (tid & 3) << 4;
        const float* Mo = M_old + (size_t)bh * HD * HD + (size_t)r * HD + c0;
#pragma unroll
        for (int i = 0; i < 4; ++i)
            *reinterpret_cast<float4*>(&Ms[r][c0 + 4 * i]) =
                *reinterpret_cast<const float4*>(Mo + 4 * i);
        if (tid < 64) Zs[tid] = Z_old[(size_t)bh * HD + tid];
        const u16* q = qbase + ((size_t)bh * LSEQ + l0 + r) * HD + c0;
#pragma unroll
        for (int i = 0; i < 4; ++i) {
            u16x4 q4 = *(const u16x4*)(q + 4 * i);
            phiQ[r][c0 + 4 * i + 0] = phif_(b2f(q4[0]));
            phiQ[r][c0 + 4 * i + 1] = phif_(b2f(q4[1]));
            phiQ[r][c0 + 4 * i + 2] = phif_(b2f(q4[2]));
            phiQ[r][c0 + 4 * i + 3] = phif_(b2f(q4[3]));
        }
    }
    __syncthreads();

    const int lr = tid >> 2, sub = tid & 3, e0 = sub << 4;
    float den = 0.f;
#pragma unroll
    for (int i = 0; i < 16; ++i) den = fmaf(phiQ[lr][e0 + i], Zs[e0 + i], den);
    den += __shfl_xor(den, 1);
    den += __shfl_xor(den, 2);
    den += 1e-6f;

    float acc[16] = {};
    for (int dd = 0; dd < 64; ++dd) {
        const float pq = phiQ[lr][dd];
#pragma unroll
        for (int i = 0; i < 16; ++i) acc[i] = fmaf(pq, Ms[dd][e0 + i], acc[i]);
    }
    const float g = gate / den;

    // merge the two KV halves
    const int row = l0 + lr;
    const float2 m0 = ml[bh * LSEQ + row];
    const float2 m1 = ml[32 * LSEQ + bh * LSEQ + row];
    const float mm = fmaxf(m0.x, m1.x);
    float a0 = exp2f(m0.x - mm) * m0.y;
    float a1 = exp2f(m1.x - mm) * m1.y;
    const float inv = 1.0f / (a0 + a1);
    a0 *= inv; a1 *= inv;

    const size_t prow = ((size_t)bh * LSEQ + row) * HD + e0;
    const u16* o0p = opart + prow;
    const u16* o1p = opart + 4194304 + prow;
    int4 o0a = *(const int4*)o0p;            // 8 bf16
    int4 o0b = *(const int4*)(o0p + 8);
    int4 o1a = *(const int4*)o1p;
    int4 o1b = *(const int4*)(o1p + 8);
    const u16* u0a = (const u16*)&o0a; const u16* u0b = (const u16*)&o0b;
    const u16* u1a = (const u16*)&o1a; const u16* u1b = (const u16*)&o1b;

    const size_t rowoff = ((size_t)b * LSEQ + row) * DM + h * HD + e0;
    u16 o[16];
#pragma unroll
    for (int i = 0; i < 8; ++i) {
        float att = a0 * b2f(u0a[i]) + a1 * b2f(u1a[i]);
        o[i] = f2b(att + g * acc[i]);
    }
#pragma unroll
    for (int i = 0; i < 8; ++i) {
        float att = a0 * b2f(u0b[i]) + a1 * b2f(u1b[i]);
        o[8 + i] = f2b(att + g * acc[8 + i]);
    }
    *(int4*)(ctxb + rowoff) = *(int4*)o;
    *(int4*)(ctxb + rowoff + 8) = *(int4*)(o + 8);
}

// ---------------------------------------------------------------------------
// MFMA flash attention, causal split-KV, DMA-staged (T3-minimal):
// K/V/Q staged via global_load_lds from PRE-SWIZZLED tile images (qt/kt/vt) —
// zero ds_write instructions, zero staging registers. Per tile: issue next
// tile's DMA BEFORE compute, vmcnt(0)+barrier after (latency hidden).
// Q overlay in buf1 (consumed into regs before first buf1 DMA).
// LDS 32KB: buf0 = K 0..8K | V 8..16K ; buf1 = 16..24K | 24..32K.
// Stores normalized partial O (bf16) + (m,l); combine merges.
// ---------------------------------------------------------------------------
__global__ __launch_bounds__(256) void flash_mfma(
    const u16* __restrict__ qt_, const u16* __restrict__ kt,
    const u16* __restrict__ vt, u16* __restrict__ opart,
    float2* __restrict__ ml) {
    __shared__ int4 smem4[2048];   // 32 KB
    char* lds = (char*)smem4;

    const int bid = blockIdx.x;
    const int qt = 15 - (bid >> 6);       // heavy q-tiles dispatch first
    const int half = (bid >> 5) & 1;
    const int bh = bid & 31;
    const int tid = threadIdx.x;
    const int w = tid >> 6;
    const int lane = tid & 63;
    const int hi = lane >> 5;
    const int l31 = lane & 31;
    const int qw0 = qt * 128 + w * 32;
    const int tdiag = qw0 >> 6;
    const int t0 = half ? (qt + 1) : 0;
    const int t1 = half ? (2 * qt + 2) : (qt + 1);   // exclusive

    // DMA staging: linear copy of pre-swizzled tile images.
    auto stage_tile = [&](int t, int base) {
        const u16* ks = kt + ((size_t)(bh * 32 + t)) * 4096;
        const u16* vs = vt + ((size_t)(bh * 32 + t)) * 4096;
#pragma unroll
        for (int j = 0; j < 2; ++j) {
            gload16(ks + tid * 8 + j * 2048, (u16*)(lds + base + w * 1024 + j * 4096));
            gload16(vs + tid * 8 + j * 2048, (u16*)(lds + base + 8192 + w * 1024 + j * 4096));
        }
    };

    // prologue: Q image (16 KB) -> buf1 region; tile t0 -> buf0
    {
        const u16* qs = qt_ + ((size_t)(bh * 16 + qt)) * 8192;
#pragma unroll
        for (int i = 0; i < 4; ++i)
            gload16(qs + tid * 8 + i * 2048, (u16*)(lds + 16384 + w * 1024 + i * 4096));
    }
    stage_tile(t0, 0);
    sync_vm0();            // Q + t0 resident

    bf16x8 qf[4];
    {
        const char* qp = lds + 16384 + ((w << 5) + l31) * 128;
        const int sw = l31 & 7;
#pragma unroll
        for (int ks = 0; ks < 4; ++ks) {
            int c = 2 * ks + hi;
            qf[ks] = *(const bf16x8*)(qp + ((c ^ sw) * 16));
        }
    }
    sync_lgkm0();          // all waves consumed Q; buf1 free for DMA

    f32x16 accO[2];
#pragma unroll
    for (int mf = 0; mf < 2; ++mf)
#pragma unroll
        for (int i = 0; i < 16; ++i) accO[mf][i] = 0.f;
    float m_run = -INFINITY, l_run = 0.f;
    const int swK = l31 & 7;
    const int vsw = (l31 >> 3) & 3;

    auto compute_tile = [&](int t, int base) {
        const char* Kb = lds + base;
        const char* Vb = lds + base + 8192;
        f32x16 st0, st1;
#pragma unroll
        for (int i = 0; i < 16; ++i) { st0[i] = 0.f; st1[i] = 0.f; }
        __builtin_amdgcn_s_setprio(1);
#pragma unroll
        for (int ks = 0; ks < 4; ++ks) {
            int cc = 2 * ks + hi;
            bf16x8 kf0 = *(const bf16x8*)(Kb + l31 * 128 + ((cc ^ swK) * 16));
            bf16x8 kf1 = *(const bf16x8*)(Kb + (32 + l31) * 128 + ((cc ^ swK) * 16));
            st0 = __builtin_amdgcn_mfma_f32_32x32x16_bf16(kf0, qf[ks], st0, 0, 0, 0);
            st1 = __builtin_amdgcn_mfma_f32_32x32x16_bf16(kf1, qf[ks], st1, 0, 0, 0);
        }
        __builtin_amdgcn_s_setprio(0);
        bf16x8 va[2][2][2];
#pragma unroll
        for (int sub = 0; sub < 2; ++sub)
#pragma unroll
            for (int kb2 = 0; kb2 < 2; ++kb2)
#pragma unroll
                for (int mf = 0; mf < 2; ++mf)
                    va[sub][kb2][mf] = *(const bf16x8*)(
                        Vb + sub * 4096 + mf * 2048 + l31 * 64 + (((kb2 * 2 + hi) ^ vsw) * 16));

        float s[32];
#pragma unroll
        for (int r = 0; r < 16; ++r) { s[r] = st0[r]; s[16 + r] = st1[r]; }
        if (t == tdiag) {
            const int qg = qw0 + l31;
#pragma unroll
            for (int r = 0; r < 32; ++r) {
                int keyg = t * 64 + (r >> 4) * 32 + (r & 3) + 8 * ((r >> 2) & 3) + 4 * hi;
                if (keyg > qg) s[r] = -INFINITY;
            }
        }
        float t16[16];
#pragma unroll
        for (int r = 0; r < 16; ++r) t16[r] = fmaxf(s[r], s[r + 16]);
        float t8[8];
#pragma unroll
        for (int r = 0; r < 8; ++r) t8[r] = fmaxf(t16[r], t16[r + 8]);
        float t4[4];
#pragma unroll
        for (int r = 0; r < 4; ++r) t4[r] = fmaxf(t8[r], t8[r + 4]);
        float pm = fmaxf(fmaxf(t4[0], t4[1]), fmaxf(t4[2], t4[3]));
        pm = fmaxf(pm, __shfl_xor(pm, 32));
        // defer-rescale, log2 domain: THR = 8*log2(e)
        if (!__all(pm - m_run <= 11.5416f)) {
            const float mn = fmaxf(m_run, pm);
            const float sc = exp2f(m_run - mn);
#pragma unroll
            for (int mf = 0; mf < 2; ++mf)
#pragma unroll
                for (int i = 0; i < 16; ++i) accO[mf][i] *= sc;
            l_run *= sc;
            m_run = mn;
        }
        float p[32];
#pragma unroll
        for (int r = 0; r < 32; ++r) p[r] = exp2f(s[r] - m_run);
        float a16[16];
#pragma unroll
        for (int r = 0; r < 16; ++r) a16[r] = p[r] + p[r + 16];
        float a8[8];
#pragma unroll
        for (int r = 0; r < 8; ++r) a8[r] = a16[r] + a16[r + 8];
        float a4[4];
#pragma unroll
        for (int r = 0; r < 4; ++r) a4[r] = a8[r] + a8[r + 4];
        float ss = (a4[0] + a4[1]) + (a4[2] + a4[3]);
        ss += __shfl_xor(ss, 32);
        l_run += ss;

        int pk[16];
#pragma unroll
        for (int i = 0; i < 16; ++i) pk[i] = cvtpkbf(p[2 * i], p[2 * i + 1]);
        int xp[16];
#pragma unroll
        for (int i = 0; i < 16; ++i) xp[i] = __shfl_xor(pk[i], 32);
        const bool hib = (hi != 0);
        union { int i[4]; bf16x8 v; } pu[4];
#pragma unroll
        for (int g = 0; g < 4; ++g) {
            const int o = g * 4;
            pu[g].i[0] = hib ? xp[o + 2] : pk[o + 0];
            pu[g].i[1] = hib ? xp[o + 3] : pk[o + 1];
            pu[g].i[2] = hib ? pk[o + 2] : xp[o + 0];
            pu[g].i[3] = hib ? pk[o + 3] : xp[o + 1];
        }
        __builtin_amdgcn_s_setprio(1);
        accO[0] = __builtin_amdgcn_mfma_f32_32x32x16_bf16(va[0][0][0], pu[0].v, accO[0], 0, 0, 0);
        accO[1] = __builtin_amdgcn_mfma_f32_32x32x16_bf16(va[0][0][1], pu[0].v, accO[1], 0, 0, 0);
        accO[0] = __builtin_amdgcn_mfma_f32_32x32x16_bf16(va[0][1][0], pu[1].v, accO[0], 0, 0, 0);
        accO[1] = __builtin_amdgcn_mfma_f32_32x32x16_bf16(va[0][1][1], pu[1].v, accO[1], 0, 0, 0);
        accO[0] = __builtin_amdgcn_mfma_f32_32x32x16_bf16(va[1][0][0], pu[2].v, accO[0], 0, 0, 0);
        accO[1] = __builtin_amdgcn_mfma_f32_32x32x16_bf16(va[1][0][1], pu[2].v, accO[1], 0, 0, 0);
        accO[0] = __builtin_amdgcn_mfma_f32_32x32x16_bf16(va[1][1][0], pu[3].v, accO[0], 0, 0, 0);
        accO[1] = __builtin_amdgcn_mfma_f32_32x32x16_bf16(va[1][1][1], pu[3].v, accO[1], 0, 0, 0);
        __builtin_amdgcn_s_setprio(0);
    };

    int curb = 0;
    for (int t = t0; t < t1; ++t) {
        if (t + 1 < t1) stage_tile(t + 1, (curb ^ 1) * 16384);  // issue early
        if (t <= tdiag) compute_tile(t, curb * 16384);
        sync_vm0();                                             // late drain
        curb ^= 1;
    }

    // ---- epilogue: normalized partial O (bf16) + (m,l) ----
    const float invl = (l_run > 0.f) ? (1.0f / l_run) : 0.f;
    const int qg = qw0 + l31;
    u16* obase = opart + (half ? 4194304 : 0) + ((size_t)bh * LSEQ + qg) * HD;
#pragma unroll
    for (int mf = 0; mf < 2; ++mf) {
#pragma unroll
        for (int g = 0; g < 4; ++g) {
            const int d4 = mf * 32 + 8 * g + 4 * hi;
            *(ull*)(obase + d4) = pack4(accO[mf][g * 4 + 0] * invl,
                                        accO[mf][g * 4 + 1] * invl,
                                        accO[mf][g * 4 + 2] * invl,
                                        accO[mf][g * 4 + 3] * invl);
        }
    }
    if (hi == 0)
        ml[(half ? 32 * LSEQ : 0) + bh * LSEQ + qg] = make_float2(m_run, l_run);
}

// ---------------------------------------------------------------------------
extern "C" void kernel_launch(void* const* d_in, const int* in_sizes, int n_in,
                              void* d_out, int out_size, void* d_ws, size_t ws_size,
                              hipStream_t stream) {
    const float* x     = (const float*)d_in[0];
    const float* wq    = (const float*)d_in[1];
    const float* wk    = (const float*)d_in[2];
    const float* wv    = (const float*)d_in[3];
    const float* wo    = (const float*)d_in[4];
    const float* gate  = (const float*)d_in[5];
    const float* decay = (const float*)d_in[6];
    const float* fcos  = (const float*)d_in[7];
    const float* fsin  = (const float*)d_in[8];
    const float* M_old = (const float*)d_in[9];
    const float* Z_old = (const float*)d_in[10];
    float* out = (float*)d_out;

    // ws layout (72 MB): xb 8MB | wqkv 6MB | wob 2MB | qt 8 | q_base 8 |
    // kt 8 | k_base 8 | vt 8 | opart (2 halves bf16) 16MB
    u16* xb     = (u16*)d_ws;
    u16* wqkv   = xb + 4194304;
    u16* wob    = wqkv + 3145728;
    u16* qt_    = wob + 1048576;
    u16* q_base = qt_ + 4194304;
    u16* kt     = q_base + 4194304;
    u16* k_base = kt + 4194304;
    u16* vt     = k_base + 4194304;
    u16* opart  = vt + 4194304;           // 2 x 4194304 u16
    float* wsf  = (float*)wqkv;           // wqkv region reused after QKV GEMM
    float* lkq  = wsf;                    // 65536 f
    float* lvq  = wsf + 65536;            // 65536 f
    float2* ml  = (float2*)(wsf + 131072);// 2 x 65536 float2 (1 MB)
    u16* ctxb   = xb;                     // reuse after QKV GEMM

    dim3 bb(256);
    cvt_all<<<dim3(4096), bb, 0, stream>>>(x, wq, wk, wv, wo, xb);

    gemm_mfma<4><<<dim3(32, 24), bb, 0, stream>>>(xb, wqkv, nullptr, q_base, qt_,
                                                  k_base, kt, vt, fcos, fsin);

    landmarks<<<dim3(NB * NH * NLM), bb, 0, stream>>>(k_base, vt, lkq, lvq);
    mem_update<<<dim3(NB * NH), bb, 0, stream>>>(lkq, lvq, M_old, Z_old, decay, out);
    flash_mfma<<<dim3(1024), bb, 0, stream>>>(qt_, kt, vt, opart, ml);
    combine<<<dim3(LSEQ / 64, NB * NH), bb, 0, stream>>>(q_base, opart, ml, M_old,
                                                         Z_old, gate, ctxb);

    gemm_mfma<1><<<dim3(32, 8), bb, 0, stream>>>(ctxb, wob, out, nullptr, nullptr,
                                                 nullptr, nullptr, nullptr, nullptr, nullptr);
}

// Round 17
// 173.524 us; speedup vs baseline: 1.1067x; 1.1067x over previous
//
#include <hip/hip_runtime.h>
#include <math.h>

#define NH 16
#define HD 64
#define NB 2
#define LSEQ 2048
#define DM 1024
#define NLM 32

// out layout: y [4194304] | M_new [131072] | Z_new [2048]
#define OUT_M 4194304
#define OUT_Z 4325376

typedef unsigned short u16;
typedef short bf16x8 __attribute__((ext_vector_type(8)));
typedef float f32x16 __attribute__((ext_vector_type(16)));
typedef unsigned short u16x4 __attribute__((ext_vector_type(4)));
typedef unsigned long long ull;

__device__ __forceinline__ float sigmoidf_(float x) { return 1.0f / (1.0f + __expf(-x)); }
__device__ __forceinline__ float phif_(float x) { return x > 0.0f ? x + 1.0f : __expf(x); }

__device__ __forceinline__ u16 f2b(float f) {
    union { float f; unsigned u; } v; v.f = f;
    unsigned r = v.u + 0x7FFFu + ((v.u >> 16) & 1u);
    return (u16)(r >> 16);
}
__device__ __forceinline__ float b2f(u16 b) {
    union { unsigned u; float f; } v; v.u = ((unsigned)b) << 16; return v.f;
}
__device__ __forceinline__ ull pack4(float a, float b, float c, float d) {
    return (ull)f2b(a) | ((ull)f2b(b) << 16) | ((ull)f2b(c) << 32) | ((ull)f2b(d) << 48);
}
__device__ __forceinline__ int cvtpkbf(float lo, float hi2) {
    int r;
    asm("v_cvt_pk_bf16_f32 %0, %1, %2" : "=v"(r) : "v"(lo), "v"(hi2));
    return r;
}
__device__ __forceinline__ void gload16(const u16* g, u16* l) {
    __builtin_amdgcn_global_load_lds(
        (const __attribute__((address_space(1))) void*)g,
        (__attribute__((address_space(3))) void*)l, 16, 0, 0);
}
// Barrier WITHOUT the compiler's vmcnt(0) drain: each wave drains its own LDS
// writes (lgkmcnt) for visibility; global->reg prefetches stay in flight (T4).
__device__ __forceinline__ void block_sync_lds() {
    __builtin_amdgcn_sched_barrier(0);
    asm volatile("s_waitcnt lgkmcnt(0)" ::: "memory");
    __builtin_amdgcn_s_barrier();
    __builtin_amdgcn_sched_barrier(0);
}

// ---------------------------------------------------------------------------
// f32 -> bf16 convert: x | wq | wk | wv | wo into contiguous dst (8M elems)
// ---------------------------------------------------------------------------
__global__ __launch_bounds__(256) void cvt_all(
    const float* __restrict__ x, const float* __restrict__ wq,
    const float* __restrict__ wk, const float* __restrict__ wv,
    const float* __restrict__ wo, u16* __restrict__ dst) {
    size_t i = ((size_t)blockIdx.x * 256 + threadIdx.x) * 8;
    const float* src;
    size_t off;
    if (i < 4194304)      { src = x;  off = i; }
    else if (i < 5242880) { src = wq; off = i - 4194304; }
    else if (i < 6291456) { src = wk; off = i - 5242880; }
    else if (i < 7340032) { src = wv; off = i - 6291456; }
    else                  { src = wo; off = i - 7340032; }
    float4 a = *(const float4*)(src + off);
    float4 b = *(const float4*)(src + off + 4);
    u16 o[8] = {f2b(a.x), f2b(a.y), f2b(a.z), f2b(a.w),
                f2b(b.x), f2b(b.y), f2b(b.z), f2b(b.w)};
    *(int4*)(dst + i) = *(int4*)o;
}

// ---------------------------------------------------------------------------
// MFMA GEMM, global_load_lds staging with pre-swizzled source + XOR-swizzled
// reads (T2 / m201 pattern). Tile 128x128, BK=64, 4 waves 2x2.
// MODE 4: fused QKV (W = [3072][1024]); q_rope scale folds 0.125*log2(e) so
//         flash can use native exp2. MODE 1: f32 row-major out.
// ---------------------------------------------------------------------------
template <int MODE>
__global__ __launch_bounds__(256) void gemm_mfma(
    const u16* __restrict__ A, const u16* __restrict__ W,
    float* __restrict__ Cf, u16* __restrict__ qb, u16* __restrict__ qrp,
    u16* __restrict__ kbp, u16* __restrict__ krp, u16* __restrict__ vbp,
    const float* __restrict__ fcos, const float* __restrict__ fsin) {
    __shared__ u16 As[128 * 64];   // 16 KB, linear (row*128B + chunk*16B)
    __shared__ u16 Ws[128 * 64];   // 16 KB
    const int tid = threadIdx.x;
    const int m0 = blockIdx.x * 128;
    const int n0 = blockIdx.y * 128;
    const int w = tid >> 6;
    const int lane = tid & 63;
    const int l31 = lane & 31;
    const int khalf = lane >> 5;
    const int wr0 = (w >> 1) * 64;
    const int wc0 = (w & 1) * 64;

    const u16* Ag = A + (size_t)m0 * DM;
    const u16* Wg = W + (size_t)n0 * DM;

    const int st_uoff[4] = {w * 4096, w * 4096 + 1024, w * 4096 + 2048, w * 4096 + 3072};
    int st_row[4], st_cc[4];
#pragma unroll
    for (int i = 0; i < 4; ++i) {
        const int off = st_uoff[i] + lane * 16;
        st_row[i] = off >> 7;
        st_cc[i] = ((off >> 4) & 7) ^ (st_row[i] & 7);
    }

    f32x16 acc[2][2];
#pragma unroll
    for (int mf = 0; mf < 2; ++mf)
#pragma unroll
        for (int nf = 0; nf < 2; ++nf)
#pragma unroll
            for (int i = 0; i < 16; ++i) acc[mf][nf][i] = 0.f;

    for (int k0 = 0; k0 < DM; k0 += 64) {
        __syncthreads();
#pragma unroll
        for (int i = 0; i < 4; ++i)
            gload16(Ag + (size_t)st_row[i] * DM + k0 + st_cc[i] * 8,
                    (u16*)((char*)As + st_uoff[i]));
#pragma unroll
        for (int i = 0; i < 4; ++i)
            gload16(Wg + (size_t)st_row[i] * DM + k0 + st_cc[i] * 8,
                    (u16*)((char*)Ws + st_uoff[i]));
        __syncthreads();
#pragma unroll
        for (int ko = 0; ko < 4; ++ko) {
            const int cl = ko * 2 + khalf;
            const int ra0 = wr0 + l31, ra1 = wr0 + 32 + l31;
            const int rb0 = wc0 + l31, rb1 = wc0 + 32 + l31;
            bf16x8 af0 = *(const bf16x8*)((char*)As + ra0 * 128 + ((cl ^ (ra0 & 7)) * 16));
            bf16x8 af1 = *(const bf16x8*)((char*)As + ra1 * 128 + ((cl ^ (ra1 & 7)) * 16));
            bf16x8 bf0 = *(const bf16x8*)((char*)Ws + rb0 * 128 + ((cl ^ (rb0 & 7)) * 16));
            bf16x8 bf1 = *(const bf16x8*)((char*)Ws + rb1 * 128 + ((cl ^ (rb1 & 7)) * 16));
            acc[0][0] = __builtin_amdgcn_mfma_f32_32x32x16_bf16(af0, bf0, acc[0][0], 0, 0, 0);
            acc[0][1] = __builtin_amdgcn_mfma_f32_32x32x16_bf16(af0, bf1, acc[0][1], 0, 0, 0);
            acc[1][0] = __builtin_amdgcn_mfma_f32_32x32x16_bf16(af1, bf0, acc[1][0], 0, 0, 0);
            acc[1][1] = __builtin_amdgcn_mfma_f32_32x32x16_bf16(af1, bf1, acc[1][1], 0, 0, 0);
        }
    }

#pragma unroll
    for (int mf = 0; mf < 2; ++mf) {
#pragma unroll
        for (int nf = 0; nf < 2; ++nf) {
            const int nn = n0 + wc0 + nf * 32 + l31;
#pragma unroll
            for (int reg = 0; reg < 16; ++reg) {
                const int m = m0 + wr0 + mf * 32 + (reg & 3) + 8 * (reg >> 2) + 4 * khalf;
                const float val = acc[mf][nf][reg];
                if (MODE == 1) {
                    Cf[(size_t)m * DM + nn] = val;
                } else {
                    const int b = m >> 11, l = m & (LSEQ - 1);
                    const int mat = nn >> 10;       // 0=q 1=k 2=v
                    const int n = nn & 1023;
                    const int h = n >> 6, d = n & 63;
                    const size_t hs = (((size_t)(b * NH + h)) * LSEQ + l) * HD + d;
                    const float p = __shfl_xor(val, 1);   // full-exec; partner d^1
                    if (mat == 2) {
                        vbp[hs] = f2b(val);
                    } else {
                        u16* bs = mat ? kbp : qb;
                        u16* rs = mat ? krp : qrp;
                        bs[hs] = f2b(val);
                        const float c = fcos[l * 32 + (d >> 1)];
                        const float s = fsin[l * 32 + (d >> 1)];
                        float o = (d & 1) ? (p * s + val * c) : (val * c - p * s);
                        if (mat == 0) o *= 0.18033688f;   // 0.125 * log2(e)
                        rs[hs] = f2b(o);
                    }
                }
            }
        }
    }
}

// ---------------------------------------------------------------------------
// Landmarks: one block per (b,h,m) chunk -> phi(k-mean), v-mean
// ---------------------------------------------------------------------------
__global__ __launch_bounds__(256) void landmarks(
    const u16* __restrict__ kbase, const u16* __restrict__ vbase,
    float* __restrict__ lkq, float* __restrict__ lvq) {
    __shared__ float redk[4][HD];
    __shared__ float redv[4][HD];
    const int bh = blockIdx.x >> 5;
    const int m = blockIdx.x & 31;
    const int tid = threadIdx.x;
    const int ls = tid >> 6;
    const int d = tid & 63;
    const u16* kb = kbase + ((size_t)bh * LSEQ + m * 64) * HD;
    const u16* vb = vbase + ((size_t)bh * LSEQ + m * 64) * HD;
    float sk = 0.f, sv = 0.f;
    for (int l = ls; l < 64; l += 4) {
        sk += b2f(kb[(size_t)l * HD + d]);
        sv += b2f(vb[(size_t)l * HD + d]);
    }
    redk[ls][d] = sk;
    redv[ls][d] = sv;
    __syncthreads();
    if (tid < 64) {
        float mk = (redk[0][d] + redk[1][d] + redk[2][d] + redk[3][d]) * (1.0f / 64.0f);
        float mv = (redv[0][d] + redv[1][d] + redv[2][d] + redv[3][d]) * (1.0f / 64.0f);
        lkq[((size_t)bh * NLM + m) * HD + d] = phif_(mk);
        lvq[((size_t)bh * NLM + m) * HD + d] = mv;
    }
}

// ---------------------------------------------------------------------------
__global__ __launch_bounds__(256) void mem_update(
    const float* __restrict__ lkq, const float* __restrict__ lvq,
    const float* __restrict__ M_old, const float* __restrict__ Z_old,
    const float* __restrict__ decay_p, float* __restrict__ out) {
    __shared__ float lk[NLM][HD];
    __shared__ float lv[NLM][HD];
    const int bh = blockIdx.x;
    const int tid = threadIdx.x;
    const float decay = sigmoidf_(decay_p[0]);
#pragma unroll
    for (int i = 0; i < 8; ++i) {
        int idx = tid + 256 * i;
        lk[idx >> 6][idx & 63] = lkq[(size_t)bh * (NLM * HD) + idx];
        lv[idx >> 6][idx & 63] = lvq[(size_t)bh * (NLM * HD) + idx];
    }
    __syncthreads();
    const size_t mo = (size_t)bh * HD * HD;
#pragma unroll
    for (int p = 0; p < 16; ++p) {
        int idx = tid + 256 * p;
        int dd = idx >> 6, e = idx & 63;
        float s = 0.f;
#pragma unroll
        for (int m = 0; m < NLM; ++m) s = fmaf(lk[m][dd], lv[m][e], s);
        out[OUT_M + mo + idx] = M_old[mo + idx] * decay + s;
    }
    if (tid < 64) {
        float s = 0.f;
#pragma unroll
        for (int m = 0; m < NLM; ++m) s += lk[m][tid];
        out[OUT_Z + (size_t)bh * HD + tid] = Z_old[(size_t)bh * HD + tid] * decay + s;
    }
}

// ---------------------------------------------------------------------------
// Combine: merge split-KV partials (normalized bf16 O + (m,l) per half) and
// add gate * (phiQ @ M_old)/den. Writes ctxb (bf16).
// ---------------------------------------------------------------------------
__global__ __launch_bounds__(256) void combine(
    const u16* __restrict__ qbase, const u16* __restrict__ opart,
    const float2* __restrict__ ml, const float* __restrict__ M_old,
    const float* __restrict__ Z_old, const float* __restrict__ gate_p,
    u16* __restrict__ ctxb) {
    __shared__ float phiQ[64][68];
    __shared__ float Ms[64][64];
    __shared__ float Zs[64];
    const int l0 = blockIdx.x * 64;
    const int bh = blockIdx.y;
    const int b = bh >> 4, h = bh & 15;
    const int tid = threadIdx.x;
    const float gate = sigmoidf_(gate_p[0]);

    {
        const int r = tid >> 2, c0 = (tid & 3) << 4;
        const float* Mo = M_old + (size_t)bh * HD * HD + (size_t)r * HD + c0;
#pragma unroll
        for (int i = 0; i < 4; ++i)
            *reinterpret_cast<float4*>(&Ms[r][c0 + 4 * i]) =
                *reinterpret_cast<const float4*>(Mo + 4 * i);
        if (tid < 64) Zs[tid] = Z_old[(size_t)bh * HD + tid];
        const u16* q = qbase + ((size_t)bh * LSEQ + l0 + r) * HD + c0;
#pragma unroll
        for (int i = 0; i < 4; ++i) {
            u16x4 q4 = *(const u16x4*)(q + 4 * i);
            phiQ[r][c0 + 4 * i + 0] = phif_(b2f(q4[0]));
            phiQ[r][c0 + 4 * i + 1] = phif_(b2f(q4[1]));
            phiQ[r][c0 + 4 * i + 2] = phif_(b2f(q4[2]));
            phiQ[r][c0 + 4 * i + 3] = phif_(b2f(q4[3]));
        }
    }
    __syncthreads();

    const int lr = tid >> 2, sub = tid & 3, e0 = sub << 4;
    float den = 0.f;
#pragma unroll
    for (int i = 0; i < 16; ++i) den = fmaf(phiQ[lr][e0 + i], Zs[e0 + i], den);
    den += __shfl_xor(den, 1);
    den += __shfl_xor(den, 2);
    den += 1e-6f;

    float acc[16] = {};
    for (int dd = 0; dd < 64; ++dd) {
        const float pq = phiQ[lr][dd];
#pragma unroll
        for (int i = 0; i < 16; ++i) acc[i] = fmaf(pq, Ms[dd][e0 + i], acc[i]);
    }
    const float g = gate / den;

    // merge the two KV halves
    const int row = l0 + lr;
    const float2 m0 = ml[bh * LSEQ + row];
    const float2 m1 = ml[32 * LSEQ + bh * LSEQ + row];
    const float mm = fmaxf(m0.x, m1.x);
    float a0 = exp2f(m0.x - mm) * m0.y;
    float a1 = exp2f(m1.x - mm) * m1.y;
    const float inv = 1.0f / (a0 + a1);
    a0 *= inv; a1 *= inv;

    const size_t prow = ((size_t)bh * LSEQ + row) * HD + e0;
    const u16* o0p = opart + prow;
    const u16* o1p = opart + 4194304 + prow;
    int4 o0a = *(const int4*)o0p;            // 8 bf16
    int4 o0b = *(const int4*)(o0p + 8);
    int4 o1a = *(const int4*)o1p;
    int4 o1b = *(const int4*)(o1p + 8);
    const u16* u0a = (const u16*)&o0a; const u16* u0b = (const u16*)&o0b;
    const u16* u1a = (const u16*)&o1a; const u16* u1b = (const u16*)&o1b;

    const size_t rowoff = ((size_t)b * LSEQ + row) * DM + h * HD + e0;
    u16 o[16];
#pragma unroll
    for (int i = 0; i < 8; ++i) {
        float att = a0 * b2f(u0a[i]) + a1 * b2f(u1a[i]);
        o[i] = f2b(att + g * acc[i]);
    }
#pragma unroll
    for (int i = 0; i < 8; ++i) {
        float att = a0 * b2f(u0b[i]) + a1 * b2f(u1b[i]);
        o[8 + i] = f2b(att + g * acc[8 + i]);
    }
    *(int4*)(ctxb + rowoff) = *(int4*)o;
    *(int4*)(ctxb + rowoff + 8) = *(int4*)(o + 8);
}

// ---------------------------------------------------------------------------
// MFMA flash attention, causal split-KV: block = (bh, qt, half), 4 waves,
// 128-row q-tile. half0: tiles [0, qt+1); half1: tiles [qt+1, 2qt+2).
// Heavy-first monotone grid order (qt = 15 - bid>>6).
// Q staged transiently in the buf1 region -> LDS 32 KB, VGPR ~124.
// Barriers use raw s_barrier + lgkmcnt(0) only (T4).
// Stores normalized partial O (bf16) + (m,l); combine merges.
// LDS 32KB: K0 0 | V0 8K | K1 16K | V1 24K  (Q overlay at 16K..32K).
// ---------------------------------------------------------------------------
__global__ __launch_bounds__(256) void flash_mfma(
    const u16* __restrict__ qr, const u16* __restrict__ kr,
    const u16* __restrict__ vv, u16* __restrict__ opart,
    float2* __restrict__ ml) {
    __shared__ int4 smem4[2048];   // 32 KB
    char* lds = (char*)smem4;

    const int bid = blockIdx.x;
    const int qt = 15 - (bid >> 6);       // heavy q-tiles dispatch first
    const int half = (bid >> 5) & 1;
    const int bh = bid & 31;
    const int q0 = qt * 128;
    const int tid = threadIdx.x;
    const int w = tid >> 6;
    const int lane = tid & 63;
    const int hi = lane >> 5;
    const int l31 = lane & 31;
    const int qw0 = q0 + w * 32;
    const int tdiag = qw0 >> 6;
    const int t0 = half ? (qt + 1) : 0;
    const int t1 = half ? (2 * qt + 2) : (qt + 1);   // exclusive
    const size_t base_bh = (size_t)bh * (LSEQ * HD);

    // ---- stage Q (128x64 bf16, row-XOR-swizzled) into buf1 region (16K) ----
#pragma unroll
    for (int i = 0; i < 4; ++i) {
        int u = tid + 256 * i;
        int row = u >> 3, c = u & 7;
        int4 val = *(const int4*)(qr + base_bh + (size_t)(q0 + row) * HD + c * 8);
        *(int4*)(lds + 16384 + row * 128 + ((c ^ (row & 7)) * 16)) = val;
    }

    // per-thread K/V staging maps (j=0,1 covers 64 rows x 8 chunks)
    int r_[2], c_[2], skoff_[2], svoff_[2];
#pragma unroll
    for (int j = 0; j < 2; ++j) {
        int u = tid + 256 * j;
        int r = u >> 3, cc = u & 7;
        r_[j] = r; c_[j] = cc;
        skoff_[j] = r * 128 + ((cc ^ (r & 7)) * 16);
        int d0 = cc << 3;
        svoff_[j] = (r >> 5) * 4096 + (d0 >> 5) * 2048 + (d0 & 31) * 64
                  + ((((r & 31) >> 3) ^ ((d0 >> 3) & 3)) * 16 + (r & 7) * 2);
    }

    int4 RAk[2], RAv[2], RBk[2], RBv[2];
    auto load_tile = [&](int t, int4* Rk, int4* Rv) {
#pragma unroll
        for (int j = 0; j < 2; ++j) {
            Rk[j] = *(const int4*)(kr + base_bh + (size_t)(t * 64 + r_[j]) * HD + c_[j] * 8);
            Rv[j] = *(const int4*)(vv + base_bh + (size_t)(t * 64 + r_[j]) * HD + c_[j] * 8);
        }
    };
    auto write_tile = [&](int base, int4* Rk, int4* Rv) {
#pragma unroll
        for (int j = 0; j < 2; ++j) {
            *(int4*)(lds + base + skoff_[j]) = Rk[j];
            union { int4 q; u16 h[8]; } uv; uv.q = Rv[j];
            char* vd = lds + base + 8192 + svoff_[j];
#pragma unroll
            for (int e = 0; e < 8; ++e) *(u16*)(vd + e * 64) = uv.h[e];
        }
    };

    load_tile(t0, RAk, RAv);
    block_sync_lds();   // Q visible

    // Q fragments from the transient overlay
    bf16x8 qf[4];
    {
        const char* qp = lds + 16384 + ((w << 5) + l31) * 128;
        const int sw = l31 & 7;
#pragma unroll
        for (int ks = 0; ks < 4; ++ks) {
            int c = 2 * ks + hi;
            qf[ks] = *(const bf16x8*)(qp + ((c ^ sw) * 16));
        }
    }
    write_tile(0, RAk, RAv);
    if (t0 + 1 < t1) load_tile(t0 + 1, RBk, RBv);
    block_sync_lds();   // buf0 ready; all Q reads drained (loop may write 16K)

    f32x16 accO[2];
#pragma unroll
    for (int mf = 0; mf < 2; ++mf)
#pragma unroll
        for (int i = 0; i < 16; ++i) accO[mf][i] = 0.f;
    float m_run = -INFINITY, l_run = 0.f;
    const int swK = l31 & 7;
    const int vsw = (l31 >> 3) & 3;

    auto compute_tile = [&](int t, int base) {
        const char* Kb = lds + base;
        const char* Vb = lds + base + 8192;
        f32x16 st0, st1;
#pragma unroll
        for (int i = 0; i < 16; ++i) { st0[i] = 0.f; st1[i] = 0.f; }
        __builtin_amdgcn_s_setprio(1);
#pragma unroll
        for (int ks = 0; ks < 4; ++ks) {
            int cc = 2 * ks + hi;
            bf16x8 kf0 = *(const bf16x8*)(Kb + l31 * 128 + ((cc ^ swK) * 16));
            bf16x8 kf1 = *(const bf16x8*)(Kb + (32 + l31) * 128 + ((cc ^ swK) * 16));
            st0 = __builtin_amdgcn_mfma_f32_32x32x16_bf16(kf0, qf[ks], st0, 0, 0, 0);
            st1 = __builtin_amdgcn_mfma_f32_32x32x16_bf16(kf1, qf[ks], st1, 0, 0, 0);
        }
        __builtin_amdgcn_s_setprio(0);
        bf16x8 va[2][2][2];
#pragma unroll
        for (int sub = 0; sub < 2; ++sub)
#pragma unroll
            for (int kb2 = 0; kb2 < 2; ++kb2)
#pragma unroll
                for (int mf = 0; mf < 2; ++mf)
                    va[sub][kb2][mf] = *(const bf16x8*)(
                        Vb + sub * 4096 + mf * 2048 + l31 * 64 + (((kb2 * 2 + hi) ^ vsw) * 16));

        float s[32];
#pragma unroll
        for (int r = 0; r < 16; ++r) { s[r] = st0[r]; s[16 + r] = st1[r]; }
        if (t == tdiag) {
            const int qg = qw0 + l31;
#pragma unroll
            for (int r = 0; r < 32; ++r) {
                int keyg = t * 64 + (r >> 4) * 32 + (r & 3) + 8 * ((r >> 2) & 3) + 4 * hi;
                if (keyg > qg) s[r] = -INFINITY;
            }
        }
        float t16[16];
#pragma unroll
        for (int r = 0; r < 16; ++r) t16[r] = fmaxf(s[r], s[r + 16]);
        float t8[8];
#pragma unroll
        for (int r = 0; r < 8; ++r) t8[r] = fmaxf(t16[r], t16[r + 8]);
        float t4[4];
#pragma unroll
        for (int r = 0; r < 4; ++r) t4[r] = fmaxf(t8[r], t8[r + 4]);
        float pm = fmaxf(fmaxf(t4[0], t4[1]), fmaxf(t4[2], t4[3]));
        pm = fmaxf(pm, __shfl_xor(pm, 32));
        // defer-rescale, log2 domain: THR = 8*log2(e)
        if (!__all(pm - m_run <= 11.5416f)) {
            const float mn = fmaxf(m_run, pm);
            const float sc = exp2f(m_run - mn);
#pragma unroll
            for (int mf = 0; mf < 2; ++mf)
#pragma unroll
                for (int i = 0; i < 16; ++i) accO[mf][i] *= sc;
            l_run *= sc;
            m_run = mn;
        }
        float p[32];
#pragma unroll
        for (int r = 0; r < 32; ++r) p[r] = exp2f(s[r] - m_run);
        float a16[16];
#pragma unroll
        for (int r = 0; r < 16; ++r) a16[r] = p[r] + p[r + 16];
        float a8[8];
#pragma unroll
        for (int r = 0; r < 8; ++r) a8[r] = a16[r] + a16[r + 8];
        float a4[4];
#pragma unroll
        for (int r = 0; r < 4; ++r) a4[r] = a8[r] + a8[r + 4];
        float ss = (a4[0] + a4[1]) + (a4[2] + a4[3]);
        ss += __shfl_xor(ss, 32);
        l_run += ss;

        int pk[16];
#pragma unroll
        for (int i = 0; i < 16; ++i) pk[i] = cvtpkbf(p[2 * i], p[2 * i + 1]);
        int xp[16];
#pragma unroll
        for (int i = 0; i < 16; ++i) xp[i] = __shfl_xor(pk[i], 32);
        const bool hib = (hi != 0);
        union { int i[4]; bf16x8 v; } pu[4];
#pragma unroll
        for (int g = 0; g < 4; ++g) {
            const int o = g * 4;
            pu[g].i[0] = hib ? xp[o + 2] : pk[o + 0];
            pu[g].i[1] = hib ? xp[o + 3] : pk[o + 1];
            pu[g].i[2] = hib ? pk[o + 2] : xp[o + 0];
            pu[g].i[3] = hib ? pk[o + 3] : xp[o + 1];
        }
        __builtin_amdgcn_s_setprio(1);
        accO[0] = __builtin_amdgcn_mfma_f32_32x32x16_bf16(va[0][0][0], pu[0].v, accO[0], 0, 0, 0);
        accO[1] = __builtin_amdgcn_mfma_f32_32x32x16_bf16(va[0][0][1], pu[0].v, accO[1], 0, 0, 0);
        accO[0] = __builtin_amdgcn_mfma_f32_32x32x16_bf16(va[0][1][0], pu[1].v, accO[0], 0, 0, 0);
        accO[1] = __builtin_amdgcn_mfma_f32_32x32x16_bf16(va[0][1][1], pu[1].v, accO[1], 0, 0, 0);
        accO[0] = __builtin_amdgcn_mfma_f32_32x32x16_bf16(va[1][0][0], pu[2].v, accO[0], 0, 0, 0);
        accO[1] = __builtin_amdgcn_mfma_f32_32x32x16_bf16(va[1][0][1], pu[2].v, accO[1], 0, 0, 0);
        accO[0] = __builtin_amdgcn_mfma_f32_32x32x16_bf16(va[1][1][0], pu[3].v, accO[0], 0, 0, 0);
        accO[1] = __builtin_amdgcn_mfma_f32_32x32x16_bf16(va[1][1][1], pu[3].v, accO[1], 0, 0, 0);
        __builtin_amdgcn_s_setprio(0);
    };

    for (int t = t0; t < t1; t += 2) {
        if (t + 1 < t1) write_tile(16384, RBk, RBv);
        if (t + 2 < t1) load_tile(t + 2, RAk, RAv);
        if (t <= tdiag) compute_tile(t, 0);
        block_sync_lds();
        if (t + 2 < t1) write_tile(0, RAk, RAv);
        if (t + 3 < t1) load_tile(t + 3, RBk, RBv);
        if (t + 1 < t1 && t + 1 <= tdiag) compute_tile(t + 1, 16384);
        block_sync_lds();
    }

    // ---- epilogue: normalized partial O (bf16) + (m,l) ----
    const float invl = (l_run > 0.f) ? (1.0f / l_run) : 0.f;
    const int qg = qw0 + l31;
    u16* obase = opart + (half ? 4194304 : 0) + ((size_t)bh * LSEQ + qg) * HD;
#pragma unroll
    for (int mf = 0; mf < 2; ++mf) {
#pragma unroll
        for (int g = 0; g < 4; ++g) {
            const int d4 = mf * 32 + 8 * g + 4 * hi;
            *(ull*)(obase + d4) = pack4(accO[mf][g * 4 + 0] * invl,
                                        accO[mf][g * 4 + 1] * invl,
                                        accO[mf][g * 4 + 2] * invl,
                                        accO[mf][g * 4 + 3] * invl);
        }
    }
    if (hi == 0)
        ml[(half ? 32 * LSEQ : 0) + bh * LSEQ + qg] = make_float2(m_run, l_run);
}

// ---------------------------------------------------------------------------
extern "C" void kernel_launch(void* const* d_in, const int* in_sizes, int n_in,
                              void* d_out, int out_size, void* d_ws, size_t ws_size,
                              hipStream_t stream) {
    const float* x     = (const float*)d_in[0];
    const float* wq    = (const float*)d_in[1];
    const float* wk    = (const float*)d_in[2];
    const float* wv    = (const float*)d_in[3];
    const float* wo    = (const float*)d_in[4];
    const float* gate  = (const float*)d_in[5];
    const float* decay = (const float*)d_in[6];
    const float* fcos  = (const float*)d_in[7];
    const float* fsin  = (const float*)d_in[8];
    const float* M_old = (const float*)d_in[9];
    const float* Z_old = (const float*)d_in[10];
    float* out = (float*)d_out;

    // ws layout (72 MB): xb 8MB | wqkv 6MB | wob 2MB | q_rope 8 | q_base 8 |
    // k_rope 8 | k_base 8 | v 8 | opart (2 halves bf16) 16MB
    u16* xb     = (u16*)d_ws;
    u16* wqkv   = xb + 4194304;
    u16* wob    = wqkv + 3145728;
    u16* q_rope = wob + 1048576;
    u16* q_base = q_rope + 4194304;
    u16* k_rope = q_base + 4194304;
    u16* k_base = k_rope + 4194304;
    u16* v      = k_base + 4194304;
    u16* opart  = v + 4194304;            // 2 x 4194304 u16
    float* wsf  = (float*)wqkv;           // wqkv region reused after QKV GEMM
    float* lkq  = wsf;                    // 65536 f
    float* lvq  = wsf + 65536;            // 65536 f
    float2* ml  = (float2*)(wsf + 131072);// 2 x 65536 float2 (1 MB)
    u16* ctxb   = xb;                     // reuse after QKV GEMM

    dim3 bb(256);
    cvt_all<<<dim3(4096), bb, 0, stream>>>(x, wq, wk, wv, wo, xb);

    gemm_mfma<4><<<dim3(32, 24), bb, 0, stream>>>(xb, wqkv, nullptr, q_base, q_rope,
                                                  k_base, k_rope, v, fcos, fsin);

    landmarks<<<dim3(NB * NH * NLM), bb, 0, stream>>>(k_base, v, lkq, lvq);
    mem_update<<<dim3(NB * NH), bb, 0, stream>>>(lkq, lvq, M_old, Z_old, decay, out);
    flash_mfma<<<dim3(1024), bb, 0, stream>>>(q_rope, k_rope, v, opart, ml);
    combine<<<dim3(LSEQ / 64, NB * NH), bb, 0, stream>>>(q_base, opart, ml, M_old,
                                                         Z_old, gate, ctxb);

    gemm_mfma<1><<<dim3(32, 8), bb, 0, stream>>>(ctxb, wob, out, nullptr, nullptr,
                                                 nullptr, nullptr, nullptr, nullptr, nullptr);
}

// Round 18
// 172.853 us; speedup vs baseline: 1.1110x; 1.0039x over previous
//
#include <hip/hip_runtime.h>
#include <math.h>

#define NH 16
#define HD 64
#define NB 2
#define LSEQ 2048
#define DM 1024
#define NLM 32

// out layout: y [4194304] | M_new [131072] | Z_new [2048]
#define OUT_M 4194304
#define OUT_Z 4325376

typedef unsigned short u16;
typedef short bf16x8 __attribute__((ext_vector_type(8)));
typedef float f32x16 __attribute__((ext_vector_type(16)));
typedef unsigned short u16x4 __attribute__((ext_vector_type(4)));
typedef unsigned long long ull;

__device__ __forceinline__ float sigmoidf_(float x) { return 1.0f / (1.0f + __expf(-x)); }
__device__ __forceinline__ float phif_(float x) { return x > 0.0f ? x + 1.0f : __expf(x); }

__device__ __forceinline__ u16 f2b(float f) {
    union { float f; unsigned u; } v; v.f = f;
    unsigned r = v.u + 0x7FFFu + ((v.u >> 16) & 1u);
    return (u16)(r >> 16);
}
__device__ __forceinline__ float b2f(u16 b) {
    union { unsigned u; float f; } v; v.u = ((unsigned)b) << 16; return v.f;
}
__device__ __forceinline__ ull pack4(float a, float b, float c, float d) {
    return (ull)f2b(a) | ((ull)f2b(b) << 16) | ((ull)f2b(c) << 32) | ((ull)f2b(d) << 48);
}
__device__ __forceinline__ int cvtpkbf(float lo, float hi2) {
    int r;
    asm("v_cvt_pk_bf16_f32 %0, %1, %2" : "=v"(r) : "v"(lo), "v"(hi2));
    return r;
}
__device__ __forceinline__ void gload16(const u16* g, u16* l) {
    __builtin_amdgcn_global_load_lds(
        (const __attribute__((address_space(1))) void*)g,
        (__attribute__((address_space(3))) void*)l, 16, 0, 0);
}
// Barrier WITHOUT the compiler's vmcnt(0) drain: each wave drains its own LDS
// writes (lgkmcnt) for visibility; global->reg prefetches stay in flight (T4).
__device__ __forceinline__ void block_sync_lds() {
    __builtin_amdgcn_sched_barrier(0);
    asm volatile("s_waitcnt lgkmcnt(0)" ::: "memory");
    __builtin_amdgcn_s_barrier();
    __builtin_amdgcn_sched_barrier(0);
}

// ---------------------------------------------------------------------------
// f32 -> bf16 convert: x | wq | wk | wv | wo into contiguous dst (8M elems)
// ---------------------------------------------------------------------------
__global__ __launch_bounds__(256) void cvt_all(
    const float* __restrict__ x, const float* __restrict__ wq,
    const float* __restrict__ wk, const float* __restrict__ wv,
    const float* __restrict__ wo, u16* __restrict__ dst) {
    size_t i = ((size_t)blockIdx.x * 256 + threadIdx.x) * 8;
    const float* src;
    size_t off;
    if (i < 4194304)      { src = x;  off = i; }
    else if (i < 5242880) { src = wq; off = i - 4194304; }
    else if (i < 6291456) { src = wk; off = i - 5242880; }
    else if (i < 7340032) { src = wv; off = i - 6291456; }
    else                  { src = wo; off = i - 7340032; }
    float4 a = *(const float4*)(src + off);
    float4 b = *(const float4*)(src + off + 4);
    u16 o[8] = {f2b(a.x), f2b(a.y), f2b(a.z), f2b(a.w),
                f2b(b.x), f2b(b.y), f2b(b.z), f2b(b.w)};
    *(int4*)(dst + i) = *(int4*)o;
}

// ---------------------------------------------------------------------------
// MFMA GEMM, global_load_lds staging with pre-swizzled source + XOR-swizzled
// reads (T2 / m201 pattern). Tile 128x128, BK=64, 4 waves 2x2.
// MODE 4: fused QKV (W = [3072][1024]); q_rope scale folds 0.125*log2(e) so
//         flash can use native exp2. MODE 1: f32 row-major out.
// ---------------------------------------------------------------------------
template <int MODE>
__global__ __launch_bounds__(256) void gemm_mfma(
    const u16* __restrict__ A, const u16* __restrict__ W,
    float* __restrict__ Cf, u16* __restrict__ qb, u16* __restrict__ qrp,
    u16* __restrict__ kbp, u16* __restrict__ krp, u16* __restrict__ vbp,
    const float* __restrict__ fcos, const float* __restrict__ fsin) {
    __shared__ u16 As[128 * 64];   // 16 KB, linear (row*128B + chunk*16B)
    __shared__ u16 Ws[128 * 64];   // 16 KB
    const int tid = threadIdx.x;
    const int m0 = blockIdx.x * 128;
    const int n0 = blockIdx.y * 128;
    const int w = tid >> 6;
    const int lane = tid & 63;
    const int l31 = lane & 31;
    const int khalf = lane >> 5;
    const int wr0 = (w >> 1) * 64;
    const int wc0 = (w & 1) * 64;

    const u16* Ag = A + (size_t)m0 * DM;
    const u16* Wg = W + (size_t)n0 * DM;

    const int st_uoff[4] = {w * 4096, w * 4096 + 1024, w * 4096 + 2048, w * 4096 + 3072};
    int st_row[4], st_cc[4];
#pragma unroll
    for (int i = 0; i < 4; ++i) {
        const int off = st_uoff[i] + lane * 16;
        st_row[i] = off >> 7;
        st_cc[i] = ((off >> 4) & 7) ^ (st_row[i] & 7);
    }

    f32x16 acc[2][2];
#pragma unroll
    for (int mf = 0; mf < 2; ++mf)
#pragma unroll
        for (int nf = 0; nf < 2; ++nf)
#pragma unroll
            for (int i = 0; i < 16; ++i) acc[mf][nf][i] = 0.f;

    for (int k0 = 0; k0 < DM; k0 += 64) {
        __syncthreads();
#pragma unroll
        for (int i = 0; i < 4; ++i)
            gload16(Ag + (size_t)st_row[i] * DM + k0 + st_cc[i] * 8,
                    (u16*)((char*)As + st_uoff[i]));
#pragma unroll
        for (int i = 0; i < 4; ++i)
            gload16(Wg + (size_t)st_row[i] * DM + k0 + st_cc[i] * 8,
                    (u16*)((char*)Ws + st_uoff[i]));
        __syncthreads();
#pragma unroll
        for (int ko = 0; ko < 4; ++ko) {
            const int cl = ko * 2 + khalf;
            const int ra0 = wr0 + l31, ra1 = wr0 + 32 + l31;
            const int rb0 = wc0 + l31, rb1 = wc0 + 32 + l31;
            bf16x8 af0 = *(const bf16x8*)((char*)As + ra0 * 128 + ((cl ^ (ra0 & 7)) * 16));
            bf16x8 af1 = *(const bf16x8*)((char*)As + ra1 * 128 + ((cl ^ (ra1 & 7)) * 16));
            bf16x8 bf0 = *(const bf16x8*)((char*)Ws + rb0 * 128 + ((cl ^ (rb0 & 7)) * 16));
            bf16x8 bf1 = *(const bf16x8*)((char*)Ws + rb1 * 128 + ((cl ^ (rb1 & 7)) * 16));
            acc[0][0] = __builtin_amdgcn_mfma_f32_32x32x16_bf16(af0, bf0, acc[0][0], 0, 0, 0);
            acc[0][1] = __builtin_amdgcn_mfma_f32_32x32x16_bf16(af0, bf1, acc[0][1], 0, 0, 0);
            acc[1][0] = __builtin_amdgcn_mfma_f32_32x32x16_bf16(af1, bf0, acc[1][0], 0, 0, 0);
            acc[1][1] = __builtin_amdgcn_mfma_f32_32x32x16_bf16(af1, bf1, acc[1][1], 0, 0, 0);
        }
    }

#pragma unroll
    for (int mf = 0; mf < 2; ++mf) {
#pragma unroll
        for (int nf = 0; nf < 2; ++nf) {
            const int nn = n0 + wc0 + nf * 32 + l31;
#pragma unroll
            for (int reg = 0; reg < 16; ++reg) {
                const int m = m0 + wr0 + mf * 32 + (reg & 3) + 8 * (reg >> 2) + 4 * khalf;
                const float val = acc[mf][nf][reg];
                if (MODE == 1) {
                    Cf[(size_t)m * DM + nn] = val;
                } else {
                    const int b = m >> 11, l = m & (LSEQ - 1);
                    const int mat = nn >> 10;       // 0=q 1=k 2=v
                    const int n = nn & 1023;
                    const int h = n >> 6, d = n & 63;
                    const size_t hs = (((size_t)(b * NH + h)) * LSEQ + l) * HD + d;
                    const float p = __shfl_xor(val, 1);   // full-exec; partner d^1
                    if (mat == 2) {
                        vbp[hs] = f2b(val);
                    } else {
                        u16* bs = mat ? kbp : qb;
                        u16* rs = mat ? krp : qrp;
                        bs[hs] = f2b(val);
                        const float c = fcos[l * 32 + (d >> 1)];
                        const float s = fsin[l * 32 + (d >> 1)];
                        float o = (d & 1) ? (p * s + val * c) : (val * c - p * s);
                        if (mat == 0) o *= 0.18033688f;   // 0.125 * log2(e)
                        rs[hs] = f2b(o);
                    }
                }
            }
        }
    }
}

// ---------------------------------------------------------------------------
// Landmarks: one block per (b,h,m) chunk -> phi(k-mean), v-mean
// ---------------------------------------------------------------------------
__global__ __launch_bounds__(256) void landmarks(
    const u16* __restrict__ kbase, const u16* __restrict__ vbase,
    float* __restrict__ lkq, float* __restrict__ lvq) {
    __shared__ float redk[4][HD];
    __shared__ float redv[4][HD];
    const int bh = blockIdx.x >> 5;
    const int m = blockIdx.x & 31;
    const int tid = threadIdx.x;
    const int ls = tid >> 6;
    const int d = tid & 63;
    const u16* kb = kbase + ((size_t)bh * LSEQ + m * 64) * HD;
    const u16* vb = vbase + ((size_t)bh * LSEQ + m * 64) * HD;
    float sk = 0.f, sv = 0.f;
    for (int l = ls; l < 64; l += 4) {
        sk += b2f(kb[(size_t)l * HD + d]);
        sv += b2f(vb[(size_t)l * HD + d]);
    }
    redk[ls][d] = sk;
    redv[ls][d] = sv;
    __syncthreads();
    if (tid < 64) {
        float mk = (redk[0][d] + redk[1][d] + redk[2][d] + redk[3][d]) * (1.0f / 64.0f);
        float mv = (redv[0][d] + redv[1][d] + redv[2][d] + redv[3][d]) * (1.0f / 64.0f);
        lkq[((size_t)bh * NLM + m) * HD + d] = phif_(mk);
        lvq[((size_t)bh * NLM + m) * HD + d] = mv;
    }
}

// ---------------------------------------------------------------------------
__global__ __launch_bounds__(256) void mem_update(
    const float* __restrict__ lkq, const float* __restrict__ lvq,
    const float* __restrict__ M_old, const float* __restrict__ Z_old,
    const float* __restrict__ decay_p, float* __restrict__ out) {
    __shared__ float lk[NLM][HD];
    __shared__ float lv[NLM][HD];
    const int bh = blockIdx.x;
    const int tid = threadIdx.x;
    const float decay = sigmoidf_(decay_p[0]);
#pragma unroll
    for (int i = 0; i < 8; ++i) {
        int idx = tid + 256 * i;
        lk[idx >> 6][idx & 63] = lkq[(size_t)bh * (NLM * HD) + idx];
        lv[idx >> 6][idx & 63] = lvq[(size_t)bh * (NLM * HD) + idx];
    }
    __syncthreads();
    const size_t mo = (size_t)bh * HD * HD;
#pragma unroll
    for (int p = 0; p < 16; ++p) {
        int idx = tid + 256 * p;
        int dd = idx >> 6, e = idx & 63;
        float s = 0.f;
#pragma unroll
        for (int m = 0; m < NLM; ++m) s = fmaf(lk[m][dd], lv[m][e], s);
        out[OUT_M + mo + idx] = M_old[mo + idx] * decay + s;
    }
    if (tid < 64) {
        float s = 0.f;
#pragma unroll
        for (int m = 0; m < NLM; ++m) s += lk[m][tid];
        out[OUT_Z + (size_t)bh * HD + tid] = Z_old[(size_t)bh * HD + tid] * decay + s;
    }
}

// ---------------------------------------------------------------------------
// Combine: merge split-KV partials (normalized bf16 O + (m,l) per half) and
// add gate * (phiQ @ M_old)/den. Writes ctxb (bf16).
// ---------------------------------------------------------------------------
__global__ __launch_bounds__(256) void combine(
    const u16* __restrict__ qbase, const u16* __restrict__ opart,
    const float2* __restrict__ ml, const float* __restrict__ M_old,
    const float* __restrict__ Z_old, const float* __restrict__ gate_p,
    u16* __restrict__ ctxb) {
    __shared__ float phiQ[64][68];
    __shared__ float Ms[64][64];
    __shared__ float Zs[64];
    const int l0 = blockIdx.x * 64;
    const int bh = blockIdx.y;
    const int b = bh >> 4, h = bh & 15;
    const int tid = threadIdx.x;
    const float gate = sigmoidf_(gate_p[0]);

    {
        const int r = tid >> 2, c0 = (tid & 3) << 4;
        const float* Mo = M_old + (size_t)bh * HD * HD + (size_t)r * HD + c0;
#pragma unroll
        for (int i = 0; i < 4; ++i)
            *reinterpret_cast<float4*>(&Ms[r][c0 + 4 * i]) =
                *reinterpret_cast<const float4*>(Mo + 4 * i);
        if (tid < 64) Zs[tid] = Z_old[(size_t)bh * HD + tid];
        const u16* q = qbase + ((size_t)bh * LSEQ + l0 + r) * HD + c0;
#pragma unroll
        for (int i = 0; i < 4; ++i) {
            u16x4 q4 = *(const u16x4*)(q + 4 * i);
            phiQ[r][c0 + 4 * i + 0] = phif_(b2f(q4[0]));
            phiQ[r][c0 + 4 * i + 1] = phif_(b2f(q4[1]));
            phiQ[r][c0 + 4 * i + 2] = phif_(b2f(q4[2]));
            phiQ[r][c0 + 4 * i + 3] = phif_(b2f(q4[3]));
        }
    }
    __syncthreads();

    const int lr = tid >> 2, sub = tid & 3, e0 = sub << 4;
    float den = 0.f;
#pragma unroll
    for (int i = 0; i < 16; ++i) den = fmaf(phiQ[lr][e0 + i], Zs[e0 + i], den);
    den += __shfl_xor(den, 1);
    den += __shfl_xor(den, 2);
    den += 1e-6f;

    float acc[16] = {};
    for (int dd = 0; dd < 64; ++dd) {
        const float pq = phiQ[lr][dd];
#pragma unroll
        for (int i = 0; i < 16; ++i) acc[i] = fmaf(pq, Ms[dd][e0 + i], acc[i]);
    }
    const float g = gate / den;

    // merge the two KV halves
    const int row = l0 + lr;
    const float2 m0 = ml[bh * LSEQ + row];
    const float2 m1 = ml[32 * LSEQ + bh * LSEQ + row];
    const float mm = fmaxf(m0.x, m1.x);
    float a0 = exp2f(m0.x - mm) * m0.y;
    float a1 = exp2f(m1.x - mm) * m1.y;
    const float inv = 1.0f / (a0 + a1);
    a0 *= inv; a1 *= inv;

    const size_t prow = ((size_t)bh * LSEQ + row) * HD + e0;
    const u16* o0p = opart + prow;
    const u16* o1p = opart + 4194304 + prow;
    int4 o0a = *(const int4*)o0p;            // 8 bf16
    int4 o0b = *(const int4*)(o0p + 8);
    int4 o1a = *(const int4*)o1p;
    int4 o1b = *(const int4*)(o1p + 8);
    const u16* u0a = (const u16*)&o0a; const u16* u0b = (const u16*)&o0b;
    const u16* u1a = (const u16*)&o1a; const u16* u1b = (const u16*)&o1b;

    const size_t rowoff = ((size_t)b * LSEQ + row) * DM + h * HD + e0;
    u16 o[16];
#pragma unroll
    for (int i = 0; i < 8; ++i) {
        float att = a0 * b2f(u0a[i]) + a1 * b2f(u1a[i]);
        o[i] = f2b(att + g * acc[i]);
    }
#pragma unroll
    for (int i = 0; i < 8; ++i) {
        float att = a0 * b2f(u0b[i]) + a1 * b2f(u1b[i]);
        o[8 + i] = f2b(att + g * acc[8 + i]);
    }
    *(int4*)(ctxb + rowoff) = *(int4*)o;
    *(int4*)(ctxb + rowoff + 8) = *(int4*)(o + 8);
}

// ---------------------------------------------------------------------------
// MFMA flash attention, causal split-KV: block = (bh, qt, half), 4 waves,
// 128-row q-tile. half0: tiles [0, qt+1); half1: tiles [qt+1, 2qt+2).
// Heavy-first monotone grid order (qt = 15 - bid>>6).
// Q staged transiently in the buf1 region -> LDS 32 KB, VGPR ~124.
// Barriers use raw s_barrier + lgkmcnt(0) only (T4).
// Stores normalized partial O (bf16) + (m,l); combine merges.
// LDS 32KB: K0 0 | V0 8K | K1 16K | V1 24K  (Q overlay at 16K..32K).
// ---------------------------------------------------------------------------
__global__ __launch_bounds__(256) void flash_mfma(
    const u16* __restrict__ qr, const u16* __restrict__ kr,
    const u16* __restrict__ vv, u16* __restrict__ opart,
    float2* __restrict__ ml) {
    __shared__ int4 smem4[2048];   // 32 KB
    char* lds = (char*)smem4;

    const int bid = blockIdx.x;
    const int qt = 15 - (bid >> 6);       // heavy q-tiles dispatch first
    const int half = (bid >> 5) & 1;
    const int bh = bid & 31;
    const int q0 = qt * 128;
    const int tid = threadIdx.x;
    const int w = tid >> 6;
    const int lane = tid & 63;
    const int hi = lane >> 5;
    const int l31 = lane & 31;
    const int qw0 = q0 + w * 32;
    const int tdiag = qw0 >> 6;
    const int t0 = half ? (qt + 1) : 0;
    const int t1 = half ? (2 * qt + 2) : (qt + 1);   // exclusive
    const size_t base_bh = (size_t)bh * (LSEQ * HD);

    // ---- stage Q (128x64 bf16, row-XOR-swizzled) into buf1 region (16K) ----
#pragma unroll
    for (int i = 0; i < 4; ++i) {
        int u = tid + 256 * i;
        int row = u >> 3, c = u & 7;
        int4 val = *(const int4*)(qr + base_bh + (size_t)(q0 + row) * HD + c * 8);
        *(int4*)(lds + 16384 + row * 128 + ((c ^ (row & 7)) * 16)) = val;
    }

    // per-thread K/V staging maps (j=0,1 covers 64 rows x 8 chunks)
    int r_[2], c_[2], skoff_[2], svoff_[2];
#pragma unroll
    for (int j = 0; j < 2; ++j) {
        int u = tid + 256 * j;
        int r = u >> 3, cc = u & 7;
        r_[j] = r; c_[j] = cc;
        skoff_[j] = r * 128 + ((cc ^ (r & 7)) * 16);
        int d0 = cc << 3;
        svoff_[j] = (r >> 5) * 4096 + (d0 >> 5) * 2048 + (d0 & 31) * 64
                  + ((((r & 31) >> 3) ^ ((d0 >> 3) & 3)) * 16 + (r & 7) * 2);
    }

    int4 RAk[2], RAv[2], RBk[2], RBv[2];
    auto load_tile = [&](int t, int4* Rk, int4* Rv) {
#pragma unroll
        for (int j = 0; j < 2; ++j) {
            Rk[j] = *(const int4*)(kr + base_bh + (size_t)(t * 64 + r_[j]) * HD + c_[j] * 8);
            Rv[j] = *(const int4*)(vv + base_bh + (size_t)(t * 64 + r_[j]) * HD + c_[j] * 8);
        }
    };
    auto write_tile = [&](int base, int4* Rk, int4* Rv) {
#pragma unroll
        for (int j = 0; j < 2; ++j) {
            *(int4*)(lds + base + skoff_[j]) = Rk[j];
            union { int4 q; u16 h[8]; } uv; uv.q = Rv[j];
            char* vd = lds + base + 8192 + svoff_[j];
#pragma unroll
            for (int e = 0; e < 8; ++e) *(u16*)(vd + e * 64) = uv.h[e];
        }
    };

    load_tile(t0, RAk, RAv);
    block_sync_lds();   // Q visible

    // Q fragments from the transient overlay
    bf16x8 qf[4];
    {
        const char* qp = lds + 16384 + ((w << 5) + l31) * 128;
        const int sw = l31 & 7;
#pragma unroll
        for (int ks = 0; ks < 4; ++ks) {
            int c = 2 * ks + hi;
            qf[ks] = *(const bf16x8*)(qp + ((c ^ sw) * 16));
        }
    }
    write_tile(0, RAk, RAv);
    if (t0 + 1 < t1) load_tile(t0 + 1, RBk, RBv);
    block_sync_lds();   // buf0 ready; all Q reads drained (loop may write 16K)

    f32x16 accO[2];
#pragma unroll
    for (int mf = 0; mf < 2; ++mf)
#pragma unroll
        for (int i = 0; i < 16; ++i) accO[mf][i] = 0.f;
    float m_run = -INFINITY, l_run = 0.f;
    const int swK = l31 & 7;
    const int vsw = (l31 >> 3) & 3;

    auto compute_tile = [&](int t, int base) {
        const char* Kb = lds + base;
        const char* Vb = lds + base + 8192;
        f32x16 st0, st1;
#pragma unroll
        for (int i = 0; i < 16; ++i) { st0[i] = 0.f; st1[i] = 0.f; }
        __builtin_amdgcn_s_setprio(1);
#pragma unroll
        for (int ks = 0; ks < 4; ++ks) {
            int cc = 2 * ks + hi;
            bf16x8 kf0 = *(const bf16x8*)(Kb + l31 * 128 + ((cc ^ swK) * 16));
            bf16x8 kf1 = *(const bf16x8*)(Kb + (32 + l31) * 128 + ((cc ^ swK) * 16));
            st0 = __builtin_amdgcn_mfma_f32_32x32x16_bf16(kf0, qf[ks], st0, 0, 0, 0);
            st1 = __builtin_amdgcn_mfma_f32_32x32x16_bf16(kf1, qf[ks], st1, 0, 0, 0);
        }
        __builtin_amdgcn_s_setprio(0);
        bf16x8 va[2][2][2];
#pragma unroll
        for (int sub = 0; sub < 2; ++sub)
#pragma unroll
            for (int kb2 = 0; kb2 < 2; ++kb2)
#pragma unroll
                for (int mf = 0; mf < 2; ++mf)
                    va[sub][kb2][mf] = *(const bf16x8*)(
                        Vb + sub * 4096 + mf * 2048 + l31 * 64 + (((kb2 * 2 + hi) ^ vsw) * 16));

        float s[32];
#pragma unroll
        for (int r = 0; r < 16; ++r) { s[r] = st0[r]; s[16 + r] = st1[r]; }
        if (t == tdiag) {
            const int qg = qw0 + l31;
#pragma unroll
            for (int r = 0; r < 32; ++r) {
                int keyg = t * 64 + (r >> 4) * 32 + (r & 3) + 8 * ((r >> 2) & 3) + 4 * hi;
                if (keyg > qg) s[r] = -INFINITY;
            }
        }
        float t16[16];
#pragma unroll
        for (int r = 0; r < 16; ++r) t16[r] = fmaxf(s[r], s[r + 16]);
        float t8[8];
#pragma unroll
        for (int r = 0; r < 8; ++r) t8[r] = fmaxf(t16[r], t16[r + 8]);
        float t4[4];
#pragma unroll
        for (int r = 0; r < 4; ++r) t4[r] = fmaxf(t8[r], t8[r + 4]);
        float pm = fmaxf(fmaxf(t4[0], t4[1]), fmaxf(t4[2], t4[3]));
        pm = fmaxf(pm, __shfl_xor(pm, 32));
        // defer-rescale, log2 domain: THR = 8*log2(e)
        if (!__all(pm - m_run <= 11.5416f)) {
            const float mn = fmaxf(m_run, pm);
            const float sc = exp2f(m_run - mn);
#pragma unroll
            for (int mf = 0; mf < 2; ++mf)
#pragma unroll
                for (int i = 0; i < 16; ++i) accO[mf][i] *= sc;
            l_run *= sc;
            m_run = mn;
        }
        float p[32];
#pragma unroll
        for (int r = 0; r < 32; ++r) p[r] = exp2f(s[r] - m_run);
        float a16[16];
#pragma unroll
        for (int r = 0; r < 16; ++r) a16[r] = p[r] + p[r + 16];
        float a8[8];
#pragma unroll
        for (int r = 0; r < 8; ++r) a8[r] = a16[r] + a16[r + 8];
        float a4[4];
#pragma unroll
        for (int r = 0; r < 4; ++r) a4[r] = a8[r] + a8[r + 4];
        float ss = (a4[0] + a4[1]) + (a4[2] + a4[3]);
        ss += __shfl_xor(ss, 32);
        l_run += ss;

        int pk[16];
#pragma unroll
        for (int i = 0; i < 16; ++i) pk[i] = cvtpkbf(p[2 * i], p[2 * i + 1]);
        int xp[16];
#pragma unroll
        for (int i = 0; i < 16; ++i) xp[i] = __shfl_xor(pk[i], 32);
        const bool hib = (hi != 0);
        union { int i[4]; bf16x8 v; } pu[4];
#pragma unroll
        for (int g = 0; g < 4; ++g) {
            const int o = g * 4;
            pu[g].i[0] = hib ? xp[o + 2] : pk[o + 0];
            pu[g].i[1] = hib ? xp[o + 3] : pk[o + 1];
            pu[g].i[2] = hib ? pk[o + 2] : xp[o + 0];
            pu[g].i[3] = hib ? pk[o + 3] : xp[o + 1];
        }
        __builtin_amdgcn_s_setprio(1);
        accO[0] = __builtin_amdgcn_mfma_f32_32x32x16_bf16(va[0][0][0], pu[0].v, accO[0], 0, 0, 0);
        accO[1] = __builtin_amdgcn_mfma_f32_32x32x16_bf16(va[0][0][1], pu[0].v, accO[1], 0, 0, 0);
        accO[0] = __builtin_amdgcn_mfma_f32_32x32x16_bf16(va[0][1][0], pu[1].v, accO[0], 0, 0, 0);
        accO[1] = __builtin_amdgcn_mfma_f32_32x32x16_bf16(va[0][1][1], pu[1].v, accO[1], 0, 0, 0);
        accO[0] = __builtin_amdgcn_mfma_f32_32x32x16_bf16(va[1][0][0], pu[2].v, accO[0], 0, 0, 0);
        accO[1] = __builtin_amdgcn_mfma_f32_32x32x16_bf16(va[1][0][1], pu[2].v, accO[1], 0, 0, 0);
        accO[0] = __builtin_amdgcn_mfma_f32_32x32x16_bf16(va[1][1][0], pu[3].v, accO[0], 0, 0, 0);
        accO[1] = __builtin_amdgcn_mfma_f32_32x32x16_bf16(va[1][1][1], pu[3].v, accO[1], 0, 0, 0);
        __builtin_amdgcn_s_setprio(0);
    };

    for (int t = t0; t < t1; t += 2) {
        if (t + 1 < t1) write_tile(16384, RBk, RBv);
        if (t + 2 < t1) load_tile(t + 2, RAk, RAv);
        if (t <= tdiag) compute_tile(t, 0);
        block_sync_lds();
        if (t + 2 < t1) write_tile(0, RAk, RAv);
        if (t + 3 < t1) load_tile(t + 3, RBk, RBv);
        if (t + 1 < t1 && t + 1 <= tdiag) compute_tile(t + 1, 16384);
        block_sync_lds();
    }

    // ---- epilogue: normalized partial O (bf16) + (m,l) ----
    const float invl = (l_run > 0.f) ? (1.0f / l_run) : 0.f;
    const int qg = qw0 + l31;
    u16* obase = opart + (half ? 4194304 : 0) + ((size_t)bh * LSEQ + qg) * HD;
#pragma unroll
    for (int mf = 0; mf < 2; ++mf) {
#pragma unroll
        for (int g = 0; g < 4; ++g) {
            const int d4 = mf * 32 + 8 * g + 4 * hi;
            *(ull*)(obase + d4) = pack4(accO[mf][g * 4 + 0] * invl,
                                        accO[mf][g * 4 + 1] * invl,
                                        accO[mf][g * 4 + 2] * invl,
                                        accO[mf][g * 4 + 3] * invl);
        }
    }
    if (hi == 0)
        ml[(half ? 32 * LSEQ : 0) + bh * LSEQ + qg] = make_float2(m_run, l_run);
}

// ---------------------------------------------------------------------------
extern "C" void kernel_launch(void* const* d_in, const int* in_sizes, int n_in,
                              void* d_out, int out_size, void* d_ws, size_t ws_size,
                              hipStream_t stream) {
    const float* x     = (const float*)d_in[0];
    const float* wq    = (const float*)d_in[1];
    const float* wk    = (const float*)d_in[2];
    const float* wv    = (const float*)d_in[3];
    const float* wo    = (const float*)d_in[4];
    const float* gate  = (const float*)d_in[5];
    const float* decay = (const float*)d_in[6];
    const float* fcos  = (const float*)d_in[7];
    const float* fsin  = (const float*)d_in[8];
    const float* M_old = (const float*)d_in[9];
    const float* Z_old = (const float*)d_in[10];
    float* out = (float*)d_out;

    // ws layout (72 MB): xb 8MB | wqkv 6MB | wob 2MB | q_rope 8 | q_base 8 |
    // k_rope 8 | k_base 8 | v 8 | opart (2 halves bf16) 16MB
    u16* xb     = (u16*)d_ws;
    u16* wqkv   = xb + 4194304;
    u16* wob    = wqkv + 3145728;
    u16* q_rope = wob + 1048576;
    u16* q_base = q_rope + 4194304;
    u16* k_rope = q_base + 4194304;
    u16* k_base = k_rope + 4194304;
    u16* v      = k_base + 4194304;
    u16* opart  = v + 4194304;            // 2 x 4194304 u16
    float* wsf  = (float*)wqkv;           // wqkv region reused after QKV GEMM
    float* lkq  = wsf;                    // 65536 f
    float* lvq  = wsf + 65536;            // 65536 f
    float2* ml  = (float2*)(wsf + 131072);// 2 x 65536 float2 (1 MB)
    u16* ctxb   = xb;                     // reuse after QKV GEMM

    dim3 bb(256);
    cvt_all<<<dim3(4096), bb, 0, stream>>>(x, wq, wk, wv, wo, xb);

    gemm_mfma<4><<<dim3(32, 24), bb, 0, stream>>>(xb, wqkv, nullptr, q_base, q_rope,
                                                  k_base, k_rope, v, fcos, fsin);

    landmarks<<<dim3(NB * NH * NLM), bb, 0, stream>>>(k_base, v, lkq, lvq);
    mem_update<<<dim3(NB * NH), bb, 0, stream>>>(lkq, lvq, M_old, Z_old, decay, out);
    flash_mfma<<<dim3(1024), bb, 0, stream>>>(q_rope, k_rope, v, opart, ml);
    combine<<<dim3(LSEQ / 64, NB * NH), bb, 0, stream>>>(q_base, opart, ml, M_old,
                                                         Z_old, gate, ctxb);

    gemm_mfma<1><<<dim3(32, 8), bb, 0, stream>>>(ctxb, wob, out, nullptr, nullptr,
                                                 nullptr, nullptr, nullptr, nullptr, nullptr);
}